// Round 1
// baseline (564.935 us; speedup 1.0000x reference)
//
#include <hip/hip_runtime.h>
#include <math.h>

#define BATCH 4
#define CH 128
#define NPIX 4096
#define DQKD 16
#define BQ 64
#define BM 64
#define NTHREADS 256

// ---------------------------------------------------------------------------
// Projection: x [B][C][N] -> Q [B][16][N], K [B][16][N], V [B][128][N]
// q[d][n] = sum_c Wq[d][c] * x[c][n] + bq[d]   (same for k, v)
// ---------------------------------------------------------------------------
__global__ __launch_bounds__(NTHREADS) void proj_kernel(
    const float* __restrict__ x,
    const float* __restrict__ Wq, const float* __restrict__ bq,
    const float* __restrict__ Wk, const float* __restrict__ bk,
    const float* __restrict__ Wv, const float* __restrict__ bv,
    float* __restrict__ Q, float* __restrict__ K, float* __restrict__ V)
{
    __shared__ float xs[CH][BQ];  // 32 KB
    const int nb  = NPIX / BQ;            // 64 tiles per batch
    const int b   = blockIdx.x / nb;
    const int n0  = (blockIdx.x % nb) * BQ;
    const int tid = threadIdx.x;
    const float* xb = x + (size_t)b * CH * NPIX;

    for (int idx = tid; idx < CH * BQ; idx += NTHREADS) {
        int c = idx >> 6, nn = idx & 63;
        xs[c][nn] = xb[(size_t)c * NPIX + n0 + nn];
    }
    __syncthreads();

    const int nn = tid & 63;
    const int g  = __builtin_amdgcn_readfirstlane(tid >> 6);  // wave id 0..3

    // 160 output rows total; wave g owns rows [g*40, g*40+40)
    for (int rr = 0; rr < 40; rr += 4) {
        const int r = g * 40 + rr;   // region boundaries (16,32) are multiples of 4
        const float* Wrow[4];
        float accv[4];
        float* dst[4];
        #pragma unroll
        for (int j = 0; j < 4; ++j) {
            int rj = r + j;
            if (rj < DQKD) {
                Wrow[j] = Wq + rj * CH;
                accv[j] = bq[rj];
                dst[j]  = Q + ((size_t)b * DQKD + rj) * NPIX;
            } else if (rj < 2 * DQKD) {
                int d = rj - DQKD;
                Wrow[j] = Wk + d * CH;
                accv[j] = bk[d];
                dst[j]  = K + ((size_t)b * DQKD + d) * NPIX;
            } else {
                int o = rj - 2 * DQKD;
                Wrow[j] = Wv + o * CH;
                accv[j] = bv[o];
                dst[j]  = V + ((size_t)b * CH + o) * NPIX;
            }
        }
        #pragma unroll 8
        for (int c = 0; c < CH; ++c) {
            float xv = xs[c][nn];
            accv[0] += Wrow[0][c] * xv;
            accv[1] += Wrow[1][c] * xv;
            accv[2] += Wrow[2][c] * xv;
            accv[3] += Wrow[3][c] * xv;
        }
        #pragma unroll
        for (int j = 0; j < 4; ++j) dst[j][n0 + nn] = accv[j];
    }
}

// ---------------------------------------------------------------------------
// Flash attention + residual.
//  energy[n][m] = sum_d Q[d][n]*K[d][m]; P = softmax_m; out[n][c] = P.V[c][m]
//  d_out[b*CN + n*C + c] = gamma * out[n][c] + x[b*CN + n*C + c]
//  (the reference reshape is a raw memory reinterpretation of [B,N,C])
// ---------------------------------------------------------------------------
__global__ __launch_bounds__(NTHREADS) void attn_kernel(
    const float* __restrict__ Q, const float* __restrict__ K, const float* __restrict__ V,
    const float* __restrict__ x, const float* __restrict__ gamma_p,
    float* __restrict__ out)
{
    __shared__ __align__(16) float Qs[DQKD][BQ];      // 4 KB
    __shared__ __align__(16) float Ks[DQKD][BM];      // 4 KB
    __shared__ __align__(16) float Vs[BM][CH + 4];    // 33 KB (pad keeps 16B align)
    __shared__ float Ps[BQ][BM + 1];                  // 16.6 KB, stride 65 -> conflict-free
    __shared__ float scale_s[BQ];

    const int nb  = NPIX / BQ;
    const int b   = blockIdx.x / nb;
    const int n0  = (blockIdx.x % nb) * BQ;
    const int tid = threadIdx.x;
    const float gamma = gamma_p[0];

    const float* Kb = K + (size_t)b * DQKD * NPIX;
    const float* Vb = V + (size_t)b * CH * NPIX;

    for (int idx = tid; idx < DQKD * BQ; idx += NTHREADS) {
        int d = idx >> 6, nn = idx & 63;
        Qs[d][nn] = Q[((size_t)b * DQKD + d) * NPIX + n0 + nn];
    }
    __syncthreads();

    // energy-phase mapping: thread -> (query qi, key-slice s of 16)
    const int qi = tid >> 2;   // 0..63
    const int s  = tid & 3;    // 0..3
    float qreg[DQKD];
    #pragma unroll
    for (int d = 0; d < DQKD; ++d) qreg[d] = Qs[d][qi];

    // PV-phase mapping: thread -> (4 queries qg*4.., 8 channels: cg*4..+3 and 64+cg*4..+3)
    const int qg = tid >> 4;   // 0..15
    const int cg = tid & 15;   // 0..15

    float m_i = -1e30f, l_i = 0.0f;
    float acc[4][8];
    #pragma unroll
    for (int j = 0; j < 4; ++j)
        #pragma unroll
        for (int cc = 0; cc < 8; ++cc) acc[j][cc] = 0.0f;

    for (int t = 0; t < NPIX / BM; ++t) {
        const int m0 = t * BM;
        __syncthreads();  // previous tile's PV reads of Ks/Vs done
        for (int idx = tid; idx < DQKD * BM; idx += NTHREADS) {
            int d = idx >> 6, mj = idx & 63;
            Ks[d][mj] = Kb[(size_t)d * NPIX + m0 + mj];
        }
        for (int idx = tid; idx < CH * BM; idx += NTHREADS) {
            int c = idx >> 6, mj = idx & 63;
            Vs[mj][c] = Vb[(size_t)c * NPIX + m0 + mj];
        }
        __syncthreads();

        // ---- energy: e[j] for key mj = s*16+j ----
        float e[16];
        #pragma unroll
        for (int j = 0; j < 16; ++j) e[j] = 0.0f;
        #pragma unroll
        for (int d = 0; d < DQKD; ++d) {
            const float qd = qreg[d];
            const float4* kp = reinterpret_cast<const float4*>(&Ks[d][s * 16]);
            #pragma unroll
            for (int i = 0; i < 4; ++i) {
                float4 kv = kp[i];
                e[4 * i + 0] += qd * kv.x;
                e[4 * i + 1] += qd * kv.y;
                e[4 * i + 2] += qd * kv.z;
                e[4 * i + 3] += qd * kv.w;
            }
        }
        // ---- online softmax ----
        float tmax = e[0];
        #pragma unroll
        for (int j = 1; j < 16; ++j) tmax = fmaxf(tmax, e[j]);
        tmax = fmaxf(tmax, __shfl_xor(tmax, 1));
        tmax = fmaxf(tmax, __shfl_xor(tmax, 2));
        const float m_new = fmaxf(m_i, tmax);
        float psum = 0.0f;
        #pragma unroll
        for (int j = 0; j < 16; ++j) {
            float p = __expf(e[j] - m_new);
            psum += p;
            Ps[qi][s * 16 + j] = p;
        }
        psum += __shfl_xor(psum, 1);
        psum += __shfl_xor(psum, 2);
        const float sc = __expf(m_i - m_new);
        l_i = l_i * sc + psum;
        m_i = m_new;
        if (s == 0) scale_s[qi] = sc;
        __syncthreads();  // Ps + scale_s visible

        // ---- PV accumulate ----
        float scj[4];
        #pragma unroll
        for (int j = 0; j < 4; ++j) scj[j] = scale_s[qg * 4 + j];
        #pragma unroll
        for (int j = 0; j < 4; ++j)
            #pragma unroll
            for (int cc = 0; cc < 8; ++cc) acc[j][cc] *= scj[j];

        #pragma unroll 2
        for (int mj = 0; mj < BM; ++mj) {
            const float4 v0 = *reinterpret_cast<const float4*>(&Vs[mj][cg * 4]);
            const float4 v1 = *reinterpret_cast<const float4*>(&Vs[mj][64 + cg * 4]);
            float vv[8];
            vv[0] = v0.x; vv[1] = v0.y; vv[2] = v0.z; vv[3] = v0.w;
            vv[4] = v1.x; vv[5] = v1.y; vv[6] = v1.z; vv[7] = v1.w;
            float pp[4];
            pp[0] = Ps[qg * 4 + 0][mj];
            pp[1] = Ps[qg * 4 + 1][mj];
            pp[2] = Ps[qg * 4 + 2][mj];
            pp[3] = Ps[qg * 4 + 3][mj];
            #pragma unroll
            for (int j = 0; j < 4; ++j)
                #pragma unroll
                for (int cc = 0; cc < 8; ++cc)
                    acc[j][cc] += pp[j] * vv[cc];
        }
    }

    // ---- finalize: normalize, stage to LDS (reuse Vs), coalesced residual write
    if (s == 0) scale_s[qi] = 1.0f / l_i;
    __syncthreads();  // all PV reads of Vs done; linv visible
    #pragma unroll
    for (int j = 0; j < 4; ++j) {
        const float linv = scale_s[qg * 4 + j];
        float4 r0, r1;
        r0.x = acc[j][0] * linv; r0.y = acc[j][1] * linv;
        r0.z = acc[j][2] * linv; r0.w = acc[j][3] * linv;
        r1.x = acc[j][4] * linv; r1.y = acc[j][5] * linv;
        r1.z = acc[j][6] * linv; r1.w = acc[j][7] * linv;
        *reinterpret_cast<float4*>(&Vs[qg * 4 + j][cg * 4])      = r0;
        *reinterpret_cast<float4*>(&Vs[qg * 4 + j][64 + cg * 4]) = r1;
    }
    __syncthreads();

    const size_t base = (size_t)b * CH * NPIX + (size_t)n0 * CH;
    for (int idx = tid; idx < BQ * CH; idx += NTHREADS) {
        int nn = idx >> 7, c = idx & 127;
        out[base + idx] = gamma * Vs[nn][c] + x[base + idx];
    }
}

extern "C" void kernel_launch(void* const* d_in, const int* in_sizes, int n_in,
                              void* d_out, int out_size, void* d_ws, size_t ws_size,
                              hipStream_t stream) {
    const float* x     = (const float*)d_in[0];
    const float* Wq    = (const float*)d_in[1];
    const float* bq    = (const float*)d_in[2];
    const float* Wk    = (const float*)d_in[3];
    const float* bk    = (const float*)d_in[4];
    const float* Wv    = (const float*)d_in[5];
    const float* bv    = (const float*)d_in[6];
    const float* gamma = (const float*)d_in[7];
    float* out = (float*)d_out;

    float* Q = (float*)d_ws;                       // 4*16*4096  floats (1 MB)
    float* K = Q + (size_t)BATCH * DQKD * NPIX;    // 1 MB
    float* V = K + (size_t)BATCH * DQKD * NPIX;    // 4*128*4096 floats (8 MB)

    dim3 grid(BATCH * (NPIX / BQ));                // 256 blocks
    proj_kernel<<<grid, NTHREADS, 0, stream>>>(x, Wq, bq, Wk, bk, Wv, bv, Q, K, V);
    attn_kernel<<<grid, NTHREADS, 0, stream>>>(Q, K, V, x, gamma, out);
}